// Round 7
// baseline (66.177 us; speedup 1.0000x reference)
//
#include <hip/hip_runtime.h>
#include <hip/hip_bf16.h>

#define BATCH 32
#define KP1   8193      // K+1
#define FEAT  128
#define SDIM  2048
#define KT    64        // k tiles per batch row (128 k each; last tile +1)
#define NBLK_GATHER (KT * BATCH)   // 2048
#define NBLK_LOSS 256
#define TOT_OUT (BATCH * KP1)      // 262176

typedef float f32x4 __attribute__((ext_vector_type(4)));

__device__ __forceinline__ float wave_reduce64(float v) {
    #pragma unroll
    for (int off = 32; off > 0; off >>= 1) v += __shfl_xor(v, off);
    return v;
}

// ---------------- kernel 1: embed y = x@W^T + b (UNnormalized) + partial sumsq
// grid (4 dc, 32 b, 2 m), 256 thr. Norm factor folded into gather via psum.
__global__ void embed_y_kernel(const float* __restrict__ x_s, const float* __restrict__ x_t,
                               const float* __restrict__ W_s, const float* __restrict__ b_s,
                               const float* __restrict__ W_t, const float* __restrict__ b_t,
                               float* __restrict__ y /* [2][32][128] */,
                               float* __restrict__ psum /* [2][32][4] */) {
    __shared__ float xsh[SDIM];
    __shared__ float ysh[32];
    int dc = blockIdx.x, b = blockIdx.y, m = blockIdx.z;
    int tid = threadIdx.x;
    const float* x    = (m ? x_t : x_s) + (size_t)b * SDIM;
    const float* W    = m ? W_t : W_s;
    const float* bias = m ? b_t : b_s;

    for (int i = tid; i < SDIM / 4; i += 256)
        ((f32x4*)xsh)[i] = ((const f32x4*)x)[i];
    __syncthreads();

    int wave = tid >> 6, lane = tid & 63;
    const f32x4* x4 = (const f32x4*)xsh;
    #pragma unroll
    for (int j = 0; j < 8; ++j) {
        int dl = wave * 8 + j;            // 0..31
        int row = dc * 32 + dl;
        const f32x4* Wr = (const f32x4*)(W + (size_t)row * SDIM);
        float acc = 0.f;
        #pragma unroll
        for (int i = 0; i < 8; ++i) {
            f32x4 w = Wr[lane + i * 64], xv = x4[lane + i * 64];
            acc += w.x * xv.x + w.y * xv.y + w.z * xv.z + w.w * xv.w;
        }
        acc = wave_reduce64(acc);
        if (lane == 0) ysh[dl] = acc + bias[row];
    }
    __syncthreads();

    if (tid < 64) {
        float v = (tid < 32) ? ysh[tid] * ysh[tid] : 0.f;
        v = wave_reduce64(v);
        if (tid == 0) psum[((size_t)m * BATCH + b) * 4 + dc] = v;
    }
    if (tid < 32)
        y[((size_t)m * BATCH + b) * FEAT + dc * 32 + tid] = ysh[tid];
}

// ---------------- kernel 2: gather + dot + exp + partial sums ----------------
// grid (64 tile, 32 b), 256 thr = 4 waves. Per unroll slot a wave owns one k:
// lanes 0-31 read the v1 row, lanes 32-63 the v2 row IN THE SAME instruction
// (1 KB coalesced per load). 8 independent k in flight per wave (8 KB).
__global__ __launch_bounds__(256) void gather_kernel(
        const float* __restrict__ mem_v1, const float* __restrict__ mem_v2,
        const float* __restrict__ y, const float* __restrict__ psum,
        const int* __restrict__ idx, const int* __restrict__ cidx,
        float* __restrict__ out_v1, float* __restrict__ out_v2,
        float* __restrict__ partials /* [NBLK_GATHER][2] */) {
    const float INVT = 14.285714285714286f;  // 1/0.07
    __shared__ int   kidx[132];
    __shared__ float ls1[4], ls2[4];
    int tile = blockIdx.x;    // 0..63
    int b    = blockIdx.y;    // 0..31
    int tid  = threadIdx.x;

    int k0 = tile * 128;
    int kn = (tile == KT - 1) ? 129 : 128;   // last tile also covers k=8192
    if (tid < kn) {
        int k = k0 + tid;
        kidx[tid] = (k == 0) ? idx[b] : cidx[(size_t)b * 8192 + (k - 1)];
    }

    // norm factors (uniform per block)
    const float* ps = psum + (size_t)b * 4;
    const float* pt = psum + (size_t)(BATCH + b) * 4;
    float cs = rsqrtf(ps[0] + ps[1] + ps[2] + ps[3]) * INVT;  // scales v2·y_s
    float ct = rsqrtf(pt[0] + pt[1] + pt[2] + pt[3]) * INVT;  // scales v1·y_t

    int lane = tid & 63, wave = tid >> 6;
    int half = lane >> 5, l32 = lane & 31;

    // lanes 0-31 dot v1 rows with y_t; lanes 32-63 dot v2 rows with y_s
    const float* mem = half ? mem_v2 : mem_v1;
    f32x4 freg = ((const f32x4*)(y + (size_t)(half ? b : BATCH + b) * FEAT))[l32];
    __syncthreads();

    float s1 = 0.f, s2 = 0.f;
    int iters = (kn + 31) >> 5;   // 4 (5 for last tile)
    for (int it = 0; it < iters; ++it) {
        int base = it * 32 + wave * 8;
        f32x4 a[8];
        int vld[8];
        #pragma unroll
        for (int u = 0; u < 8; ++u) {
            int kl = base + u;
            vld[u] = (kl < kn);
            int fi = kidx[vld[u] ? kl : 0];
            a[u] = ((const f32x4*)(mem + (size_t)fi * FEAT))[l32];
        }
        #pragma unroll
        for (int u = 0; u < 8; ++u) {
            float p = a[u].x * freg.x + a[u].y * freg.y + a[u].z * freg.z + a[u].w * freg.w;
            #pragma unroll
            for (int off = 16; off > 0; off >>= 1) p += __shfl_xor(p, off);
            if (vld[u]) {
                int kg = k0 + base + u;
                if (lane == 0) {          // v1·y_t -> out_v2
                    float ov2 = expf(p * ct);
                    out_v2[(size_t)b * KP1 + kg] = ov2;
                    s2 += ov2;
                } else if (lane == 32) {  // v2·y_s -> out_v1
                    float ov1 = expf(p * cs);
                    out_v1[(size_t)b * KP1 + kg] = ov1;
                    s1 += ov1;
                }
            }
        }
    }
    s1 = wave_reduce64(s1);
    s2 = wave_reduce64(s2);
    if (lane == 0) { ls1[wave] = s1; ls2[wave] = s2; }
    __syncthreads();
    if (tid == 0) {
        int pbid = b * KT + tile;
        partials[2 * pbid + 0] = ls1[0] + ls1[1] + ls1[2] + ls1[3];
        partials[2 * pbid + 1] = ls2[0] + ls2[1] + ls2[2] + ls2[3];
    }
}

// ---------------- kernel 3: fused Z-reduce + per-element loss terms ----------
__global__ void lossZ_kernel(const float* __restrict__ partials,
                             const float* __restrict__ out_v1, const float* __restrict__ out_v2,
                             double* __restrict__ lpart) {
    __shared__ float sh1[256], sh2[256];
    __shared__ float zsh[2];
    int tid = threadIdx.x;
    float a1 = 0.f, a2 = 0.f;
    #pragma unroll
    for (int i = 0; i < NBLK_GATHER / 256; ++i) {
        int j = i * 256 + tid;
        a1 += partials[2 * j];
        a2 += partials[2 * j + 1];
    }
    sh1[tid] = a1; sh2[tid] = a2; __syncthreads();
    for (int s = 128; s > 0; s >>= 1) {
        if (tid < s) { sh1[tid] += sh1[tid + s]; sh2[tid] += sh2[tid + s]; }
        __syncthreads();
    }
    if (tid == 0) {
        const float scale = 1000000.0f / (float)TOT_OUT;  // mean * N_DATA
        zsh[0] = sh1[0] * scale;   // Z_v1
        zsh[1] = sh2[0] * scale;   // Z_v2
    }
    __syncthreads();
    float z0 = zsh[0], z1 = zsh[1];

    const float cc = 8192.0f / 1000000.0f;   // m * Pn
    const float ce = cc + 1e-7f;             // c + EPS
    int gid = blockIdx.x * 256 + tid;
    int stride = gridDim.x * 256;
    double acc = 0.0;
    for (int e = gid; e < 2 * TOT_OUT; e += stride) {
        int arr = (e >= TOT_OUT);
        int r   = arr ? (e - TOT_OUT) : e;
        int k   = r % KP1;
        float o = (arr ? out_v2[r] : out_v1[r]) / (arr ? z1 : z0);
        float denom = o + ce;
        float term = (k == 0) ? logf(o / denom) : logf(cc / denom);
        acc += (double)term;
    }
    __shared__ double shd[256];
    shd[tid] = acc; __syncthreads();
    for (int s = 128; s > 0; s >>= 1) {
        if (tid < s) shd[tid] += shd[tid + s];
        __syncthreads();
    }
    if (tid == 0) lpart[blockIdx.x] = shd[0];
}

// ---------------- kernel 4: final reduce -> loss ----------------
__global__ void final_kernel(const double* __restrict__ lpart, float* __restrict__ out) {
    __shared__ double sh[256];
    int tid = threadIdx.x;
    sh[tid] = lpart[tid];   // NBLK_LOSS == 256
    __syncthreads();
    for (int s = 128; s > 0; s >>= 1) {
        if (tid < s) sh[tid] += sh[tid + s];
        __syncthreads();
    }
    if (tid == 0) out[0] = (float)(-sh[0] / (double)BATCH);
}

extern "C" void kernel_launch(void* const* d_in, const int* in_sizes, int n_in,
                              void* d_out, int out_size, void* d_ws, size_t ws_size,
                              hipStream_t stream) {
    const float* x_s   = (const float*)d_in[0];
    const float* x_t   = (const float*)d_in[1];
    const float* W_s   = (const float*)d_in[2];
    const float* b_s   = (const float*)d_in[3];
    const float* W_t   = (const float*)d_in[4];
    const float* b_t   = (const float*)d_in[5];
    const float* mem_v1 = (const float*)d_in[6];
    const float* mem_v2 = (const float*)d_in[7];
    const int*   idx   = (const int*)d_in[8];
    const int*   cidx  = (const int*)d_in[9];
    float* out = (float*)d_out;

    // workspace layout (floats)
    float* ws = (float*)d_ws;
    float* y      = ws;                         // 2*32*128 = 8192
    float* psum   = y + 2 * BATCH * FEAT;       // 2*32*4 = 256
    float* out_v1 = psum + 256;                 // 262176
    float* out_v2 = out_v1 + TOT_OUT;           // 262176
    float* parts  = out_v2 + TOT_OUT;           // 2*2048 = 4096
    size_t off_f = (size_t)(parts + 2 * NBLK_GATHER - ws);
    off_f = (off_f + 1) & ~(size_t)1;           // 8B align
    double* lpart = (double*)(ws + off_f);      // 256 doubles

    embed_y_kernel<<<dim3(4, BATCH, 2), 256, 0, stream>>>(x_s, x_t, W_s, b_s, W_t, b_t,
                                                           y, psum);
    gather_kernel<<<dim3(KT, BATCH), 256, 0, stream>>>(mem_v1, mem_v2, y, psum,
                                                        idx, cidx, out_v1, out_v2, parts);
    lossZ_kernel<<<NBLK_LOSS, 256, 0, stream>>>(parts, out_v1, out_v2, lpart);
    final_kernel<<<1, 256, 0, stream>>>(lpart, out);
}

// Round 8
// 64.713 us; speedup vs baseline: 1.0226x; 1.0226x over previous
//
#include <hip/hip_runtime.h>
#include <hip/hip_bf16.h>

#define BATCH 32
#define KP1   8193      // K+1
#define FEAT  128
#define SDIM  2048
#define KT    64        // k tiles per batch row (128 k each; last tile +1)
#define NBLK_GATHER (KT * BATCH)   // 2048
#define NBLK_LOSS 256
#define TOT_OUT (BATCH * KP1)      // 262176

typedef float f32x4 __attribute__((ext_vector_type(4)));

__device__ __forceinline__ float wave_reduce64(float v) {
    #pragma unroll
    for (int off = 32; off > 0; off >>= 1) v += __shfl_xor(v, off);
    return v;
}

// ---------------- kernel 1: embed y = x@W^T + b (UNnormalized) + partial sumsq
// grid (4 dc, 32 b, 2 m), 256 thr. Norm factor folded into gather via psum.
__global__ void embed_y_kernel(const float* __restrict__ x_s, const float* __restrict__ x_t,
                               const float* __restrict__ W_s, const float* __restrict__ b_s,
                               const float* __restrict__ W_t, const float* __restrict__ b_t,
                               float* __restrict__ y /* [2][32][128] */,
                               float* __restrict__ psum /* [2][32][4] */) {
    __shared__ float xsh[SDIM];
    __shared__ float ysh[32];
    int dc = blockIdx.x, b = blockIdx.y, m = blockIdx.z;
    int tid = threadIdx.x;
    const float* x    = (m ? x_t : x_s) + (size_t)b * SDIM;
    const float* W    = m ? W_t : W_s;
    const float* bias = m ? b_t : b_s;

    for (int i = tid; i < SDIM / 4; i += 256)
        ((f32x4*)xsh)[i] = ((const f32x4*)x)[i];
    __syncthreads();

    int wave = tid >> 6, lane = tid & 63;
    const f32x4* x4 = (const f32x4*)xsh;
    #pragma unroll
    for (int j = 0; j < 8; ++j) {
        int dl = wave * 8 + j;            // 0..31
        int row = dc * 32 + dl;
        const f32x4* Wr = (const f32x4*)(W + (size_t)row * SDIM);
        float acc = 0.f;
        #pragma unroll
        for (int i = 0; i < 8; ++i) {
            f32x4 w = Wr[lane + i * 64], xv = x4[lane + i * 64];
            acc += w.x * xv.x + w.y * xv.y + w.z * xv.z + w.w * xv.w;
        }
        acc = wave_reduce64(acc);
        if (lane == 0) ysh[dl] = acc + bias[row];
    }
    __syncthreads();

    if (tid < 64) {
        float v = (tid < 32) ? ysh[tid] * ysh[tid] : 0.f;
        v = wave_reduce64(v);
        if (tid == 0) psum[((size_t)m * BATCH + b) * 4 + dc] = v;
    }
    if (tid < 32)
        y[((size_t)m * BATCH + b) * FEAT + dc * 32 + tid] = ysh[tid];
}

// ---------------- kernel 2: gather + dot + exp + partial sums ----------------
// grid (64 tile, 32 b), 256 thr = 4 waves. Each wave owns one k per unroll slot:
// lanes 0-31 read the v1 row, lanes 32-63 the v2 row IN THE SAME instruction
// (1 KB coalesced per load). 4 independent k in flight per wave. Regular loads
// (no nt). Half-reduce = 5 shfl. lane0 -> out_v2 term, lane32 -> out_v1 term.
__global__ __launch_bounds__(256) void gather_kernel(
        const float* __restrict__ mem_v1, const float* __restrict__ mem_v2,
        const float* __restrict__ y, const float* __restrict__ psum,
        const int* __restrict__ idx, const int* __restrict__ cidx,
        float* __restrict__ out_v1, float* __restrict__ out_v2,
        float* __restrict__ partials /* [NBLK_GATHER][2] */) {
    const float INVT = 14.285714285714286f;  // 1/0.07
    __shared__ int   kidx[132];
    __shared__ float ls1[4], ls2[4];
    int tile = blockIdx.x;    // 0..63
    int b    = blockIdx.y;    // 0..31
    int tid  = threadIdx.x;

    int k0 = tile * 128;
    int kn = (tile == KT - 1) ? 129 : 128;   // last tile also covers k=8192
    if (tid < kn) {
        int k = k0 + tid;
        kidx[tid] = (k == 0) ? idx[b] : cidx[(size_t)b * 8192 + (k - 1)];
    }

    // norm factors (uniform per block)
    const float* ps = psum + (size_t)b * 4;
    const float* pt = psum + (size_t)(BATCH + b) * 4;
    float cs = rsqrtf(ps[0] + ps[1] + ps[2] + ps[3]) * INVT;  // scales v2·y_s
    float ct = rsqrtf(pt[0] + pt[1] + pt[2] + pt[3]) * INVT;  // scales v1·y_t

    int lane = tid & 63, wave = tid >> 6;
    int half = lane >> 5, l32 = lane & 31;

    // lanes 0-31 dot v1 rows with y_t; lanes 32-63 dot v2 rows with y_s
    const float* mem = half ? mem_v2 : mem_v1;
    f32x4 freg = ((const f32x4*)(y + (size_t)(half ? b : BATCH + b) * FEAT))[l32];
    __syncthreads();

    float s1 = 0.f, s2 = 0.f;
    int iters = (kn + 15) >> 4;   // 8 (9 for last tile)
    for (int it = 0; it < iters; ++it) {
        int base = it * 16 + wave * 4;
        f32x4 a[4];
        int vld[4];
        #pragma unroll
        for (int u = 0; u < 4; ++u) {
            int kl = base + u;
            vld[u] = (kl < kn);
            int fi = kidx[vld[u] ? kl : 0];
            a[u] = ((const f32x4*)(mem + (size_t)fi * FEAT))[l32];
        }
        #pragma unroll
        for (int u = 0; u < 4; ++u) {
            float p = a[u].x * freg.x + a[u].y * freg.y + a[u].z * freg.z + a[u].w * freg.w;
            #pragma unroll
            for (int off = 16; off > 0; off >>= 1) p += __shfl_xor(p, off);
            if (vld[u]) {
                int kg = k0 + base + u;
                if (lane == 0) {          // v1·y_t -> out_v2
                    float ov2 = expf(p * ct);
                    out_v2[(size_t)b * KP1 + kg] = ov2;
                    s2 += ov2;
                } else if (lane == 32) {  // v2·y_s -> out_v1
                    float ov1 = expf(p * cs);
                    out_v1[(size_t)b * KP1 + kg] = ov1;
                    s1 += ov1;
                }
            }
        }
    }
    s1 = wave_reduce64(s1);
    s2 = wave_reduce64(s2);
    if (lane == 0) { ls1[wave] = s1; ls2[wave] = s2; }
    __syncthreads();
    if (tid == 0) {
        int pbid = b * KT + tile;
        partials[2 * pbid + 0] = ls1[0] + ls1[1] + ls1[2] + ls1[3];
        partials[2 * pbid + 1] = ls2[0] + ls2[1] + ls2[2] + ls2[3];
    }
}

// ---------------- kernel 3: fused Z-reduce + per-element loss terms ----------
__global__ void lossZ_kernel(const float* __restrict__ partials,
                             const float* __restrict__ out_v1, const float* __restrict__ out_v2,
                             double* __restrict__ lpart) {
    __shared__ float sh1[256], sh2[256];
    __shared__ float zsh[2];
    int tid = threadIdx.x;
    float a1 = 0.f, a2 = 0.f;
    #pragma unroll
    for (int i = 0; i < NBLK_GATHER / 256; ++i) {
        int j = i * 256 + tid;
        a1 += partials[2 * j];
        a2 += partials[2 * j + 1];
    }
    sh1[tid] = a1; sh2[tid] = a2; __syncthreads();
    for (int s = 128; s > 0; s >>= 1) {
        if (tid < s) { sh1[tid] += sh1[tid + s]; sh2[tid] += sh2[tid + s]; }
        __syncthreads();
    }
    if (tid == 0) {
        const float scale = 1000000.0f / (float)TOT_OUT;  // mean * N_DATA
        zsh[0] = sh1[0] * scale;   // Z_v1
        zsh[1] = sh2[0] * scale;   // Z_v2
    }
    __syncthreads();
    float z0 = zsh[0], z1 = zsh[1];

    const float cc = 8192.0f / 1000000.0f;   // m * Pn
    const float ce = cc + 1e-7f;             // c + EPS
    int gid = blockIdx.x * 256 + tid;
    int stride = gridDim.x * 256;
    double acc = 0.0;
    for (int e = gid; e < 2 * TOT_OUT; e += stride) {
        int arr = (e >= TOT_OUT);
        int r   = arr ? (e - TOT_OUT) : e;
        int k   = r % KP1;
        float o = (arr ? out_v2[r] : out_v1[r]) / (arr ? z1 : z0);
        float denom = o + ce;
        float term = (k == 0) ? logf(o / denom) : logf(cc / denom);
        acc += (double)term;
    }
    __shared__ double shd[256];
    shd[tid] = acc; __syncthreads();
    for (int s = 128; s > 0; s >>= 1) {
        if (tid < s) shd[tid] += shd[tid + s];
        __syncthreads();
    }
    if (tid == 0) lpart[blockIdx.x] = shd[0];
}

// ---------------- kernel 4: final reduce -> loss ----------------
__global__ void final_kernel(const double* __restrict__ lpart, float* __restrict__ out) {
    __shared__ double sh[256];
    int tid = threadIdx.x;
    sh[tid] = lpart[tid];   // NBLK_LOSS == 256
    __syncthreads();
    for (int s = 128; s > 0; s >>= 1) {
        if (tid < s) sh[tid] += sh[tid + s];
        __syncthreads();
    }
    if (tid == 0) out[0] = (float)(-sh[0] / (double)BATCH);
}

extern "C" void kernel_launch(void* const* d_in, const int* in_sizes, int n_in,
                              void* d_out, int out_size, void* d_ws, size_t ws_size,
                              hipStream_t stream) {
    const float* x_s   = (const float*)d_in[0];
    const float* x_t   = (const float*)d_in[1];
    const float* W_s   = (const float*)d_in[2];
    const float* b_s   = (const float*)d_in[3];
    const float* W_t   = (const float*)d_in[4];
    const float* b_t   = (const float*)d_in[5];
    const float* mem_v1 = (const float*)d_in[6];
    const float* mem_v2 = (const float*)d_in[7];
    const int*   idx   = (const int*)d_in[8];
    const int*   cidx  = (const int*)d_in[9];
    float* out = (float*)d_out;

    // workspace layout (floats)
    float* ws = (float*)d_ws;
    float* y      = ws;                         // 2*32*128 = 8192
    float* psum   = y + 2 * BATCH * FEAT;       // 2*32*4 = 256
    float* out_v1 = psum + 256;                 // 262176
    float* out_v2 = out_v1 + TOT_OUT;           // 262176
    float* parts  = out_v2 + TOT_OUT;           // 2*2048 = 4096
    size_t off_f = (size_t)(parts + 2 * NBLK_GATHER - ws);
    off_f = (off_f + 1) & ~(size_t)1;           // 8B align
    double* lpart = (double*)(ws + off_f);      // 256 doubles

    embed_y_kernel<<<dim3(4, BATCH, 2), 256, 0, stream>>>(x_s, x_t, W_s, b_s, W_t, b_t,
                                                           y, psum);
    gather_kernel<<<dim3(KT, BATCH), 256, 0, stream>>>(mem_v1, mem_v2, y, psum,
                                                        idx, cidx, out_v1, out_v2, parts);
    lossZ_kernel<<<NBLK_LOSS, 256, 0, stream>>>(parts, out_v1, out_v2, lpart);
    final_kernel<<<1, 256, 0, stream>>>(lpart, out);
}